// Round 7
// baseline (319.732 us; speedup 1.0000x reference)
//
#include <hip/hip_runtime.h>

// Shapes (fixed): B=4, L=4096, DIM=1024, INNER=512, DSTATE=8, DTRANK=64, KSZ=3
// BL = 16384 rows. Chunked scan: 128 chunks x 32 steps, chunk-major summaries.

using bf16x8 = __attribute__((ext_vector_type(8))) short;
using f32x4  = __attribute__((ext_vector_type(4))) float;

__device__ __forceinline__ unsigned short f2bf(float f) {
  unsigned int u = __float_as_uint(f);
  u = u + 0x7fffu + ((u >> 16) & 1u);   // round-to-nearest-even
  return (unsigned short)(u >> 16);
}

// fast softplus: log1p(exp(x)) via hardware exp/log; exact passthrough for x>15
__device__ __forceinline__ float fsoftplus(float x) {
  return (x > 15.f) ? x : __logf(1.f + __expf(x));
}

__device__ __forceinline__ float ftanh(float x) {
  float v = fminf(fmaxf(x, -15.f), 15.f);
  float e = __expf(2.f * v);
  return (e - 1.f) / (e + 1.f);
}

// ---------------- unified prep: all fp32->bf16 conversions, ONE launch -----
__device__ __forceinline__ void cvt4(const float* __restrict__ in,
                                     unsigned short* __restrict__ out, int i) {
  float4 v = ((const float4*)in)[i];
  ushort4 o;
  o.x = f2bf(v.x); o.y = f2bf(v.y); o.z = f2bf(v.z); o.w = f2bf(v.w);
  ((ushort4*)out)[i] = o;
}

// grid = 18720: [0,16384) x | [16384,17408) W_in | [17408,18432) W_out |
//               [18432,18464) W_dt | [18464,18720) W_xproj pad+cvt
__global__ __launch_bounds__(256) void prep_all(
    const float* __restrict__ x, const float* __restrict__ Win,
    const float* __restrict__ Wout, const float* __restrict__ Wdt,
    const float* __restrict__ Wxp,
    unsigned short* __restrict__ xbf, unsigned short* __restrict__ winbf,
    unsigned short* __restrict__ woutbf, unsigned short* __restrict__ wdbf,
    unsigned short* __restrict__ wxpbf) {
  int b = blockIdx.x, t = threadIdx.x;
  if (b < 16384)      cvt4(x,    xbf,    b * 256 + t);
  else if (b < 17408) cvt4(Win,  winbf,  (b - 16384) * 256 + t);
  else if (b < 18432) cvt4(Wout, woutbf, (b - 17408) * 256 + t);
  else if (b < 18464) cvt4(Wdt,  wdbf,   (b - 18432) * 256 + t);
  else {
    int i = (b - 18464) * 256 + t;  // 128*512 elems, rows 80..127 = 0
    int row = i >> 9;
    wxpbf[i] = (row < 80) ? f2bf(Wxp[i]) : (unsigned short)0;
  }
}

// ========== 128x128 m97-style GEMM core (small shapes), fused epilogues ====
// A: MxK row-major bf16, B: NxK row-major bf16 (B^T layout).

// proj GEMM: M=16384, N=128, K=512. Fused prep: cols 0-63 -> dtr bf16,
// 64-71 -> tanh -> bterm, 72-79 -> tanh -> cterm, 80-127 discarded.
__global__ __launch_bounds__(256) void gemm_proj128(
    const unsigned short* __restrict__ A,
    const unsigned short* __restrict__ B,
    unsigned short* __restrict__ dtr, float* __restrict__ bterm,
    float* __restrict__ cterm, int M, int N, int K) {
  __shared__ short As[128 * 32];
  __shared__ short Bs[128 * 32];
  const int m0 = blockIdx.x * 128;
  const int lane = threadIdx.x & 63;
  const int wv = threadIdx.x >> 6;
  const int wm = (wv >> 1) * 64;
  const int wn = (wv & 1) * 64;
  f32x4 acc[4][4] = {};
  const int row_a = wv * 32 + (lane >> 2);
  const int koff = (lane & 3) * 8;
  const unsigned short* gA = A + (size_t)(m0 + row_a) * K + koff;
  const unsigned short* gB = B + (size_t)row_a * K + koff;
  short* lA = &As[(wv * 32) * 32];
  short* lB = &Bs[(wv * 32) * 32];
  const int r = lane & 15;
  const int q = lane >> 4;
  for (int k0 = 0; k0 < K; k0 += 32) {
    __syncthreads();
    __builtin_amdgcn_global_load_lds((const __attribute__((address_space(1))) void*)(const void*)gA,
                                     (__attribute__((address_space(3))) void*)(void*)lA, 16, 0, 0);
    __builtin_amdgcn_global_load_lds((const __attribute__((address_space(1))) void*)(const void*)(gA + 16 * K),
                                     (__attribute__((address_space(3))) void*)(void*)(lA + 16 * 32), 16, 0, 0);
    __builtin_amdgcn_global_load_lds((const __attribute__((address_space(1))) void*)(const void*)gB,
                                     (__attribute__((address_space(3))) void*)(void*)lB, 16, 0, 0);
    __builtin_amdgcn_global_load_lds((const __attribute__((address_space(1))) void*)(const void*)(gB + 16 * K),
                                     (__attribute__((address_space(3))) void*)(void*)(lB + 16 * 32), 16, 0, 0);
    gA += 32; gB += 32;
    __syncthreads();
    bf16x8 av[4], bv[4];
#pragma unroll
    for (int i = 0; i < 4; ++i)
      av[i] = *(const bf16x8*)&As[(wm + i * 16 + r) * 32 + q * 8];
#pragma unroll
    for (int j = 0; j < 4; ++j)
      bv[j] = *(const bf16x8*)&Bs[(wn + j * 16 + r) * 32 + q * 8];
#pragma unroll
    for (int i = 0; i < 4; ++i)
#pragma unroll
      for (int j = 0; j < 4; ++j)
        acc[i][j] = __builtin_amdgcn_mfma_f32_16x16x32_bf16(av[i], bv[j], acc[i][j], 0, 0, 0);
  }
  // C/D layout: col = lane&15, row = (lane>>4)*4 + reg
#pragma unroll
  for (int i = 0; i < 4; ++i)
#pragma unroll
    for (int j = 0; j < 4; ++j) {
      const int col = wn + j * 16 + r;
#pragma unroll
      for (int t = 0; t < 4; ++t) {
        const int row = m0 + wm + i * 16 + q * 4 + t;
        float v = acc[i][j][t];
        if (col < 64)      dtr[(size_t)row * 64 + col] = f2bf(v);
        else if (col < 72) bterm[(size_t)row * 8 + (col - 64)] = ftanh(v);
        else if (col < 80) cterm[(size_t)row * 8 + (col - 72)] = ftanh(v);
      }
    }
}

// ======== dt GEMM + fused scan phase 1 ====================================
// GEMM: M=16384, N=512, K=64; delta = clip(softplus(acc + b_dt[n]), 1e-4, 1).
// A 128-row m-tile = one b, 4 scan chunks of 32 l; a 128-col n-tile = 128
// channels. So each block holds delta for exactly 4 (chunk x 128ch) scan-p1
// units. Epilogue: write delta -> draw (global, for p3) AND -> LDS tile
// (two 64-row passes, [64][129] f32 = 33KB overlaying dead As/Bs), then run
// the p1 recurrence in-kernel (identical loop order/values -> bit-identical
// Aprod/Bpart), eliminating the 33.5MB draw re-read + one launch.
// LDS 33KB -> 4 blocks/CU; launch_bounds(256,4) caps VGPR at 128.
__global__ __launch_bounds__(256, 4) void gemm_dt_scan1(
    const unsigned short* __restrict__ A,
    const unsigned short* __restrict__ B,
    const float* __restrict__ bdt,
    const float* __restrict__ xb, const float* __restrict__ bterm,
    const float* __restrict__ A_log,
    float* __restrict__ draw,
    float* __restrict__ Aprod, float* __restrict__ Bpart,
    int M, int N, int K) {
  __shared__ float arena[64 * 129];       // 33KB: As/Bs (16KB) then delta tile
  short* As = (short*)arena;              // 128*32 shorts = 8KB
  short* Bs = (short*)arena + 4096;       // 8KB
  const int m0 = blockIdx.x * 128;
  const int n0 = blockIdx.y * 128;
  const int lane = threadIdx.x & 63;
  const int wv = threadIdx.x >> 6;
  const int wm = (wv >> 1) * 64;
  const int wn = (wv & 1) * 64;
  f32x4 acc[4][4] = {};
  const int row_a = wv * 32 + (lane >> 2);
  const int koff = (lane & 3) * 8;
  const unsigned short* gA = A + (size_t)(m0 + row_a) * K + koff;
  const unsigned short* gB = B + (size_t)(n0 + row_a) * K + koff;
  short* lA = &As[(wv * 32) * 32];
  short* lB = &Bs[(wv * 32) * 32];
  const int r = lane & 15;
  const int q = lane >> 4;
  for (int k0 = 0; k0 < K; k0 += 32) {
    __syncthreads();
    __builtin_amdgcn_global_load_lds((const __attribute__((address_space(1))) void*)(const void*)gA,
                                     (__attribute__((address_space(3))) void*)(void*)lA, 16, 0, 0);
    __builtin_amdgcn_global_load_lds((const __attribute__((address_space(1))) void*)(const void*)(gA + 16 * K),
                                     (__attribute__((address_space(3))) void*)(void*)(lA + 16 * 32), 16, 0, 0);
    __builtin_amdgcn_global_load_lds((const __attribute__((address_space(1))) void*)(const void*)gB,
                                     (__attribute__((address_space(3))) void*)(void*)lB, 16, 0, 0);
    __builtin_amdgcn_global_load_lds((const __attribute__((address_space(1))) void*)(const void*)(gB + 16 * K),
                                     (__attribute__((address_space(3))) void*)(void*)(lB + 16 * 32), 16, 0, 0);
    gA += 32; gB += 32;
    __syncthreads();
    bf16x8 av[4], bv[4];
#pragma unroll
    for (int i = 0; i < 4; ++i)
      av[i] = *(const bf16x8*)&As[(wm + i * 16 + r) * 32 + q * 8];
#pragma unroll
    for (int j = 0; j < 4; ++j)
      bv[j] = *(const bf16x8*)&Bs[(wn + j * 16 + r) * 32 + q * 8];
#pragma unroll
    for (int i = 0; i < 4; ++i)
#pragma unroll
      for (int j = 0; j < 4; ++j)
        acc[i][j] = __builtin_amdgcn_mfma_f32_16x16x32_bf16(av[i], bv[j], acc[i][j], 0, 0, 0);
  }
  // bias per output column (loaded once)
  float bb4[4];
#pragma unroll
  for (int j = 0; j < 4; ++j) bb4[j] = bdt[n0 + wn + j * 16 + r];
  // scan setup: this thread's channel (same for both passes)
  const int cl = threadIdx.x & 127;            // local channel 0..127
  const int cg = n0 + cl;                      // global channel
  const int b  = m0 >> 12;                     // batch
  const int l0 = m0 & 4095;                    // first l of this m-tile
  float na[8];
  {
    float4 a0 = *(const float4*)&A_log[cg * 8];
    float4 a1 = *(const float4*)&A_log[cg * 8 + 4];
    na[0] = a0.x; na[1] = a0.y; na[2] = a0.z; na[3] = a0.w;
    na[4] = a1.x; na[5] = a1.y; na[6] = a1.z; na[7] = a1.w;
#pragma unroll
    for (int s = 0; s < 8; ++s) na[s] = -(fsoftplus(na[s]) + 1e-4f);
  }
  float (*dl)[129] = (float(*)[129])arena;     // delta tile, 64 rows/pass
  __syncthreads();                             // As/Bs reads all done
#pragma unroll 1
  for (int pass = 0; pass < 2; ++pass) {
    // ---- write phase: waves owning rows pass*64..+63 fill LDS + draw ----
    if ((wv >> 1) == pass) {
#pragma unroll
      for (int j = 0; j < 4; ++j) {
        const int col = wn + j * 16 + r;
#pragma unroll
        for (int i = 0; i < 4; ++i)
#pragma unroll
          for (int t = 0; t < 4; ++t) {
            const int rl = i * 16 + q * 4 + t;   // row within pass block
            float v = acc[i][j][t] + bb4[j];
            float delta = fminf(fmaxf(fsoftplus(v), 1e-4f), 1.f);
            draw[(size_t)(m0 + pass * 64 + rl) * N + n0 + col] = delta;
            dl[rl][col] = delta;
          }
      }
    }
    __syncthreads();
    // ---- p1 phase: 2 chunks, 128 channels each; 1 unit/thread ----
    {
      const int chl = (pass << 1) + (threadIdx.x >> 7);  // local chunk 0..3
      const int chunk = (l0 >> 5) + chl;                 // chunk within b
      const int lr0 = (chl & 1) * 32;                    // LDS row base
      size_t xbase = ((size_t)b * 4096 + l0 + chl * 32) * 512 + cg;
      size_t bbase = ((size_t)b * 4096 + l0 + chl * 32) * 8;
      float S[8] = {}, Ap[8] = {1.f, 1.f, 1.f, 1.f, 1.f, 1.f, 1.f, 1.f};
      for (int i = 0; i < 32; ++i) {
        float delta = dl[lr0 + i][cl];
        float xv = xb[xbase];
        float4 bt0 = *(const float4*)&bterm[bbase];
        float4 bt1 = *(const float4*)&bterm[bbase + 4];
        float bt[8] = {bt0.x, bt0.y, bt0.z, bt0.w, bt1.x, bt1.y, bt1.z, bt1.w};
#pragma unroll
        for (int s = 0; s < 8; ++s) {
          float dec = fminf(fmaxf(__expf(delta * na[s]), 1e-4f), 1.f);
          float btx = bt[s] * xv;
          S[s] = dec * S[s] + (btx - dec * btx);
          Ap[s] *= dec;
        }
        xbase += 512; bbase += 8;
      }
      size_t o = (size_t)chunk * 16384 + ((size_t)(b * 512 + cg)) * 8;
      *(float4*)&Aprod[o]     = make_float4(Ap[0], Ap[1], Ap[2], Ap[3]);
      *(float4*)&Aprod[o + 4] = make_float4(Ap[4], Ap[5], Ap[6], Ap[7]);
      *(float4*)&Bpart[o]     = make_float4(S[0], S[1], S[2], S[3]);
      *(float4*)&Bpart[o + 4] = make_float4(S[4], S[5], S[6], S[7]);
    }
    __syncthreads();   // pass 1 write reuses the same LDS rows
  }
}

// ================= 256x256 8-phase GEMM (big shapes) ======================
// Round-2 structure (measured 42.9-43.2us, 0 bank conflicts):
// reads-at-phase-start -> stage -> [vmcnt] -> barrier -> lgkmcnt(0) -> MFMA.
// C[m,n] = sum_k A[m,k]*B[n,k].  BM=BN=256, BK=64, 8 waves, 128 KiB LDS.
// Slot layout [row(128)][col(64) bf16] with XOR swizzle col^=((row&7)<<3);
// linear gload_lds dest + pre-swizzled global source (involution).
__device__ __forceinline__ void g256_stage(short* lds, int slot,
    const unsigned short* sp, int ktIdx, int wvLds, int K) {
  const unsigned short* s = sp + ktIdx * 64;
  __builtin_amdgcn_global_load_lds((const __attribute__((address_space(1))) void*)s,
      (__attribute__((address_space(3))) void*)(lds + slot * 8192 + wvLds), 16, 0, 0);
  __builtin_amdgcn_global_load_lds((const __attribute__((address_space(1))) void*)(s + (size_t)64 * K),
      (__attribute__((address_space(3))) void*)(lds + slot * 8192 + 4096 + wvLds), 16, 0, 0);
}

template <int PAR, int MH, int NHLO, bool RA, bool RB, int SSLOT, bool VM, bool HINT>
__device__ __forceinline__ void g256_phase(
    short* lds, int aSlotOff, int bSlotOff, int aoff, int boff, int wvLds,
    bf16x8 (&av)[4][2], bf16x8 (&bv)[4][2], f32x4 (&acc)[8][4],
    const unsigned short* sp, int ktIdx, int K) {
  if (RA) {
#pragma unroll
    for (int ii = 0; ii < 4; ++ii) {
      av[ii][0] = *(const bf16x8*)&lds[PAR * 4 * 8192 + aSlotOff + MH * 4096 + ii * 1024 + aoff];
      av[ii][1] = *(const bf16x8*)&lds[PAR * 4 * 8192 + aSlotOff + MH * 4096 + ii * 1024 + (aoff ^ 32)];
    }
  }
  if (RB) {
#pragma unroll
    for (int jj = 0; jj < 2; ++jj) {
      bv[NHLO + jj][0] = *(const bf16x8*)&lds[(PAR * 4 + 2) * 8192 + bSlotOff + (NHLO + jj) * 1024 + boff];
      bv[NHLO + jj][1] = *(const bf16x8*)&lds[(PAR * 4 + 2) * 8192 + bSlotOff + (NHLO + jj) * 1024 + (boff ^ 32)];
    }
  }
  g256_stage(lds, SSLOT, sp, ktIdx, wvLds, K);
  if (HINT) asm volatile("s_waitcnt lgkmcnt(8)");
  if (VM) asm volatile("s_waitcnt vmcnt(4)" ::: "memory");
  __builtin_amdgcn_s_barrier();
  asm volatile("s_waitcnt lgkmcnt(0)" ::: "memory");
  __builtin_amdgcn_s_setprio(1);
#pragma unroll
  for (int ii = 0; ii < 4; ++ii)
#pragma unroll
    for (int jj = 0; jj < 2; ++jj) {
      acc[MH * 4 + ii][NHLO + jj] = __builtin_amdgcn_mfma_f32_16x16x32_bf16(
          av[ii][0], bv[NHLO + jj][0], acc[MH * 4 + ii][NHLO + jj], 0, 0, 0);
      acc[MH * 4 + ii][NHLO + jj] = __builtin_amdgcn_mfma_f32_16x16x32_bf16(
          av[ii][1], bv[NHLO + jj][1], acc[MH * 4 + ii][NHLO + jj], 0, 0, 0);
    }
  __builtin_amdgcn_s_setprio(0);
  __builtin_amdgcn_s_barrier();
}

__global__ __launch_bounds__(512, 2) void gemm256_bt(
    const unsigned short* __restrict__ A,
    const unsigned short* __restrict__ B,
    float* __restrict__ C, int M, int N, int K) {
  __shared__ short lds[8 * 8192];  // 128 KiB
  const int nmt = M >> 8;
  const int bid = blockIdx.x;
  // XCD swizzle for A-panel reuse: each XCD owns (nmt/8) m-tiles x ALL
  // n-tiles, so the 4 blocks sharing an A panel are co-resident on ONE XCD.
  const int g = nmt >> 3;
  const int xcd = bid & 7;
  const int loc = bid >> 3;
  const int mtile = xcd * g + (loc % g);
  const int ntile = loc / g;
  const int m0 = mtile << 8, n0 = ntile << 8;
  const int tid = threadIdx.x;
  const int w = tid >> 6, lane = tid & 63;
  const int r = lane & 15, q = lane >> 4;
  const int wrow = w >> 2, wcol = w & 3;
  // staging: dest row tid>>3, stored col (tid&7)*8 (linear); source col is
  // the swizzle-inverse (XOR involution), stays in the same 128-B line:
  const int srow = tid >> 3;
  const int scol = ((tid & 7) ^ (srow & 7)) << 3;
  const unsigned short* pA0 = A + (size_t)(m0 + srow) * K + scol;
  const unsigned short* pA1 = A + (size_t)(m0 + 128 + srow) * K + scol;
  const unsigned short* pB0 = B + (size_t)(n0 + srow) * K + scol;
  const unsigned short* pB1 = B + (size_t)(n0 + 128 + srow) * K + scol;
  const int wvLds = w * 512;
  const int aSlotOff = wrow * 8192;
  const int bSlotOff = (wcol >> 1) * 8192;
  const int swzc = (q * 8) ^ ((r & 7) << 3);
  const int aoff = r * 64 + swzc;
  const int boff = (wcol & 1) * 4096 + r * 64 + swzc;
  bf16x8 av[4][2], bv[4][2];
  f32x4 acc[8][4] = {};
  const int NT = K >> 6;   // K-tiles (even, >=4)
  const int NI = NT >> 1;
  // prologue: K-tile 0 full (s0-s3) + K-tile 1 B halves (s6,s7)
  g256_stage(lds, 0, pA0, 0, wvLds, K);
  g256_stage(lds, 1, pA1, 0, wvLds, K);
  g256_stage(lds, 2, pB0, 0, wvLds, K);
  g256_stage(lds, 3, pB1, 0, wvLds, K);
  g256_stage(lds, 6, pB0, 1, wvLds, K);
  g256_stage(lds, 7, pB1, 1, wvLds, K);
  asm volatile("s_waitcnt vmcnt(4)" ::: "memory");  // s0-s3 landed
  __builtin_amdgcn_s_barrier();
#pragma unroll 1
  for (int it = 0; it < NI; ++it) {
    const int ktO  = 2 * it + 1;
    const int ktE2 = (2 * it + 2 < NT) ? 2 * it + 2 : NT - 1;  // clamp (tail: dead)
    const int ktO2 = (2 * it + 3 < NT) ? 2 * it + 3 : NT - 1;
    g256_phase<0, 0, 0, true,  true,  4, false, true >(lds, aSlotOff, bSlotOff, aoff, boff, wvLds, av, bv, acc, pA0, ktO,  K);
    g256_phase<0, 0, 2, false, true,  5, false, false>(lds, aSlotOff, bSlotOff, aoff, boff, wvLds, av, bv, acc, pA1, ktO,  K);
    g256_phase<0, 1, 2, true,  false, 2, false, false>(lds, aSlotOff, bSlotOff, aoff, boff, wvLds, av, bv, acc, pB0, ktE2, K);
    g256_phase<0, 1, 0, false, false, 0, true,  false>(lds, aSlotOff, bSlotOff, aoff, boff, wvLds, av, bv, acc, pA0, ktE2, K);
    g256_phase<1, 0, 0, true,  true,  1, false, true >(lds, aSlotOff, bSlotOff, aoff, boff, wvLds, av, bv, acc, pA1, ktE2, K);
    g256_phase<1, 0, 2, false, true,  3, false, false>(lds, aSlotOff, bSlotOff, aoff, boff, wvLds, av, bv, acc, pB1, ktE2, K);
    g256_phase<1, 1, 2, true,  false, 6, false, false>(lds, aSlotOff, bSlotOff, aoff, boff, wvLds, av, bv, acc, pB0, ktO2, K);
    g256_phase<1, 1, 0, false, false, 7, true,  false>(lds, aSlotOff, bSlotOff, aoff, boff, wvLds, av, bv, acc, pB1, ktO2, K);
  }
  asm volatile("s_waitcnt vmcnt(0) lgkmcnt(0)" ::: "memory");
  // epilogue: C/D layout col = lane&15, row = (lane>>4)*4 + reg
  float* Cw = C + (size_t)(m0 + wrow * 128) * N + n0 + wcol * 64;
#pragma unroll
  for (int ii = 0; ii < 8; ++ii)
#pragma unroll
    for (int jj = 0; jj < 4; ++jj)
#pragma unroll
      for (int t = 0; t < 4; ++t)
        Cw[(size_t)(ii * 16 + q * 4 + t) * N + jj * 16 + r] = acc[ii][jj][t];
}

// -------- depthwise conv (k=3, pad=1) + SiLU, rolling-window over 16 rows --
__global__ __launch_bounds__(256) void conv_silu_roll(
    const float* __restrict__ h, const float* __restrict__ Kx, const float* __restrict__ Kz,
    float* __restrict__ xb, unsigned short* __restrict__ xbbf,
    unsigned short* __restrict__ cat) {
  const int c4 = threadIdx.x << 2;          // channel group base (0..1020)
  const int bt = blockIdx.x >> 8;           // batch
  const int lt = blockIdx.x & 255;          // l-tile (16 rows each)
  const int l0 = lt << 4;
  const float* Kp; int c;
  if (c4 < 512) { Kp = Kx; c = c4; } else { Kp = Kz; c = c4 - 512; }
  const float4* K4 = (const float4*)(Kp + c * 3);  // 12 floats, 16B-aligned
  const float4 ka = K4[0], kb = K4[1], kc = K4[2];
  size_t rowbase = ((size_t)bt * 4096 + l0) * 1024 + c4;   // h/cat index, row l0
  size_t xrow    = ((size_t)bt * 4096 + l0) * 512 + c4;    // xb/xbbf index
  const float4 zero = make_float4(0.f, 0.f, 0.f, 0.f);
  float4 um = (l0 > 0) ? *(const float4*)(h + rowbase - 1024) : zero;
  float4 u0 = *(const float4*)(h + rowbase);
#pragma unroll 4
  for (int s = 0; s < 16; ++s) {
    const int l = l0 + s;
    float4 up = (l < 4095) ? *(const float4*)(h + rowbase + 1024) : zero;
    float v0 = um.x * ka.x + u0.x * ka.y + up.x * ka.z;
    float v1 = um.y * ka.w + u0.y * kb.x + up.y * kb.y;
    float v2 = um.z * kb.z + u0.z * kb.w + up.z * kc.x;
    float v3 = um.w * kc.y + u0.w * kc.z + up.w * kc.w;
    float o0 = v0 / (1.f + __expf(-v0));
    float o1 = v1 / (1.f + __expf(-v1));
    float o2 = v2 / (1.f + __expf(-v2));
    float o3 = v3 / (1.f + __expf(-v3));
    ushort4 ob;
    ob.x = f2bf(o0); ob.y = f2bf(o1); ob.z = f2bf(o2); ob.w = f2bf(o3);
    if (c4 < 512) {
      *(float4*)(xb + xrow) = make_float4(o0, o1, o2, o3);
      *(ushort4*)(xbbf + xrow) = ob;
    } else {
      *(ushort4*)(cat + rowbase) = ob;
    }
    um = u0; u0 = up;
    rowbase += 1024; xrow += 512;
  }
}

// 256 blocks x 64 threads: same 16384 series, spread over all 256 CUs.
__global__ __launch_bounds__(64) void scan_p2(
    const float* __restrict__ Aprod, const float* __restrict__ Bpart,
    float* __restrict__ initst) {
  int t = blockIdx.x * 64 + threadIdx.x;  // 16384 threads: one (b,c,s)
  float st = 0.f;
  for (int cb = 0; cb < 128; cb += 8) {
    float a[8], bb[8];
#pragma unroll
    for (int j = 0; j < 8; ++j) {
      size_t o = (size_t)(cb + j) * 16384 + t;
      a[j] = Aprod[o]; bb[j] = Bpart[o];
    }
#pragma unroll
    for (int j = 0; j < 8; ++j) {
      size_t o = (size_t)(cb + j) * 16384 + t;
      initst[o] = st;
      st = a[j] * st + bb[j];
    }
  }
}

__global__ __launch_bounds__(256) void scan_p3(
    const float* __restrict__ delta_in, const float* __restrict__ bterm,
    const float* __restrict__ cterm, const float* __restrict__ xb,
    const float* __restrict__ A_log, const float* __restrict__ Dp,
    const float* __restrict__ initst, unsigned short* __restrict__ cat) {
  int tid = threadIdx.x;
  int gid = blockIdx.x;
  int chunk = gid & 127, half = (gid >> 7) & 1, b = gid >> 8;
  int c = half * 256 + tid;
  float4 a0 = *(const float4*)&A_log[c * 8];
  float4 a1 = *(const float4*)&A_log[c * 8 + 4];
  float na[8] = {a0.x, a0.y, a0.z, a0.w, a1.x, a1.y, a1.z, a1.w};
#pragma unroll
  for (int s = 0; s < 8; ++s) na[s] = -(fsoftplus(na[s]) + 1e-4f);
  float Dv = Dp[c];
  size_t o = (size_t)chunk * 16384 + ((size_t)(b * 512 + c)) * 8;
  float4 s0 = *(const float4*)&initst[o];
  float4 s1 = *(const float4*)&initst[o + 4];
  float S[8] = {s0.x, s0.y, s0.z, s0.w, s1.x, s1.y, s1.z, s1.w};
  int l0 = chunk * 32;
  size_t base  = ((size_t)b * 4096 + l0) * 512 + c;
  size_t bbase = ((size_t)b * 4096 + l0) * 8;
  size_t cbase = ((size_t)b * 4096 + l0) * 1024 + c;   // y -> cat[..., :512]
  for (int i = 0; i < 32; ++i) {
    float delta = delta_in[base];
    float xv = xb[base];
    float4 bt0 = *(const float4*)&bterm[bbase];
    float4 bt1 = *(const float4*)&bterm[bbase + 4];
    float4 ct0 = *(const float4*)&cterm[bbase];
    float4 ct1 = *(const float4*)&cterm[bbase + 4];
    float bt[8] = {bt0.x, bt0.y, bt0.z, bt0.w, bt1.x, bt1.y, bt1.z, bt1.w};
    float ct[8] = {ct0.x, ct0.y, ct0.z, ct0.w, ct1.x, ct1.y, ct1.z, ct1.w};
    float acc = Dv * xv;
#pragma unroll
    for (int s = 0; s < 8; ++s) {
      float dec = fminf(fmaxf(__expf(delta * na[s]), 1e-4f), 1.f);
      float btx = bt[s] * xv;
      S[s] = dec * S[s] + (btx - dec * btx);
      acc += S[s] * ct[s];
    }
    cat[cbase] = f2bf(acc);
    base += 512; bbase += 8; cbase += 1024;
  }
}

// ---------------- launch ----------------
extern "C" void kernel_launch(void* const* d_in, const int* in_sizes, int n_in,
                              void* d_out, int out_size, void* d_ws, size_t ws_size,
                              hipStream_t stream) {
  (void)in_sizes; (void)n_in; (void)out_size; (void)ws_size;
  const float* x       = (const float*)d_in[0];
  const float* W_in    = (const float*)d_in[1];
  const float* Kx      = (const float*)d_in[2];
  const float* Kz      = (const float*)d_in[3];
  const float* W_xproj = (const float*)d_in[4];
  const float* W_dt    = (const float*)d_in[5];
  const float* b_dt    = (const float*)d_in[6];
  const float* A_log   = (const float*)d_in[7];
  const float* Dp      = (const float*)d_in[8];
  const float* W_out   = (const float*)d_in[9];
  float* out = (float*)d_out;

  // workspace layout (133.4 MB) with dead-buffer overlays
  char* w = (char*)d_ws;
  unsigned short* xbf  = (unsigned short*)(w);               // 33.5MB x bf16; reused as cat
  float* xb    = (float*)(w + 33554432);                     // 33.5MB fp32 xb (scan)
  float* draw  = (float*)(w + 67108864);                     // 33.5MB delta (fused softplus)
  float* bterm = (float*)(w + 100663296);                    // 0.5MB
  float* cterm = (float*)(w + 101187584);                    // 0.5MB
  float* Aprod = (float*)(w + 101711872);                    // 8MB [chunk][bcs]
  float* Bpart = (float*)(w + 110100480);                    // 8MB
  float* initst = (float*)(w + 118489088);                   // 8MB
  unsigned short* winbf  = (unsigned short*)(w + 126877696); // 2MB
  unsigned short* woutbf = (unsigned short*)(w + 128974848); // 2MB
  unsigned short* dtr    = (unsigned short*)(w + 131072000); // 2MB (16384x64 bf16)
  unsigned short* wxp_bf = (unsigned short*)(w + 133169152); // 128KB
  unsigned short* wd_bf  = (unsigned short*)(w + 133300224); // 64KB  (end 133365760)
  unsigned short* xbbf = (unsigned short*)Aprod;             // 16.8MB overlay; dead before dt+p1
  float* h = out;  // d_out doubles as h scratch (fully rewritten by final GEMM)

  // all fp32->bf16 conversions in one launch
  prep_all<<<18720, 256, 0, stream>>>(x, W_in, W_out, W_dt, W_xproj,
                                      xbf, winbf, woutbf, wd_bf, wxp_bf);

  // big GEMMs: 256x256 8-phase kernel, grid = (16384/256)*(1024/256) = 256
  gemm256_bt<<<256, 512, 0, stream>>>(xbf, winbf, h, 16384, 1024, 1024);

  conv_silu_roll<<<1024, 256, 0, stream>>>(h, Kx, Kz, xb, xbbf, xbf /*cat*/);

  // proj GEMM with fused dtr/bterm/cterm epilogue (proj never materialized)
  gemm_proj128<<<128, 256, 0, stream>>>(xbbf, wxp_bf, dtr, bterm, cterm, 16384, 128, 512);
  // dt GEMM with fused softplus+clip epilogue AND fused scan phase 1
  // (xbbf overlay on Aprod is consumed by gemm_proj128 BEFORE this runs;
  //  gemm_dt_scan1 reads dtr, writes draw + Aprod/Bpart)
  gemm_dt_scan1<<<dim3(128, 4), 256, 0, stream>>>(
      dtr, wd_bf, b_dt, xb, bterm, A_log, draw, Aprod, Bpart, 16384, 512, 64);

  scan_p2<<<256, 64, 0, stream>>>(Aprod, Bpart, initst);
  scan_p3<<<1024, 256, 0, stream>>>(draw, bterm, cterm, xb, A_log, Dp, initst, xbf /*cat*/);

  gemm256_bt<<<256, 512, 0, stream>>>(xbf, woutbf, out, 16384, 1024, 1024);
}

// Round 8
// 305.775 us; speedup vs baseline: 1.0456x; 1.0456x over previous
//
#include <hip/hip_runtime.h>

// Shapes (fixed): B=4, L=4096, DIM=1024, INNER=512, DSTATE=8, DTRANK=64, KSZ=3
// BL = 16384 rows. Chunked scan: 128 chunks x 32 steps, chunk-major summaries.

using bf16x8 = __attribute__((ext_vector_type(8))) short;
using f32x4  = __attribute__((ext_vector_type(4))) float;

__device__ __forceinline__ unsigned short f2bf(float f) {
  unsigned int u = __float_as_uint(f);
  u = u + 0x7fffu + ((u >> 16) & 1u);   // round-to-nearest-even
  return (unsigned short)(u >> 16);
}

// fast softplus: log1p(exp(x)) via hardware exp/log; exact passthrough for x>15
__device__ __forceinline__ float fsoftplus(float x) {
  return (x > 15.f) ? x : __logf(1.f + __expf(x));
}

__device__ __forceinline__ float ftanh(float x) {
  float v = fminf(fmaxf(x, -15.f), 15.f);
  float e = __expf(2.f * v);
  return (e - 1.f) / (e + 1.f);
}

// ---------------- unified prep: all fp32->bf16 conversions, ONE launch -----
__device__ __forceinline__ void cvt4(const float* __restrict__ in,
                                     unsigned short* __restrict__ out, int i) {
  float4 v = ((const float4*)in)[i];
  ushort4 o;
  o.x = f2bf(v.x); o.y = f2bf(v.y); o.z = f2bf(v.z); o.w = f2bf(v.w);
  ((ushort4*)out)[i] = o;
}

// grid = 18720: [0,16384) x | [16384,17408) W_in | [17408,18432) W_out |
//               [18432,18464) W_dt | [18464,18720) W_xproj pad+cvt
__global__ __launch_bounds__(256) void prep_all(
    const float* __restrict__ x, const float* __restrict__ Win,
    const float* __restrict__ Wout, const float* __restrict__ Wdt,
    const float* __restrict__ Wxp,
    unsigned short* __restrict__ xbf, unsigned short* __restrict__ winbf,
    unsigned short* __restrict__ woutbf, unsigned short* __restrict__ wdbf,
    unsigned short* __restrict__ wxpbf) {
  int b = blockIdx.x, t = threadIdx.x;
  if (b < 16384)      cvt4(x,    xbf,    b * 256 + t);
  else if (b < 17408) cvt4(Win,  winbf,  (b - 16384) * 256 + t);
  else if (b < 18432) cvt4(Wout, woutbf, (b - 17408) * 256 + t);
  else if (b < 18464) cvt4(Wdt,  wdbf,   (b - 18432) * 256 + t);
  else {
    int i = (b - 18464) * 256 + t;  // 128*512 elems, rows 80..127 = 0
    int row = i >> 9;
    wxpbf[i] = (row < 80) ? f2bf(Wxp[i]) : (unsigned short)0;
  }
}

// ========== 128x128 m97-style GEMM core (small shapes), fused epilogues ====
// A: MxK row-major bf16, B: NxK row-major bf16 (B^T layout).

// proj GEMM: M=16384, N=128, K=512. Fused prep: cols 0-63 -> dtr bf16,
// 64-71 -> tanh -> bterm, 72-79 -> tanh -> cterm, 80-127 discarded.
__global__ __launch_bounds__(256) void gemm_proj128(
    const unsigned short* __restrict__ A,
    const unsigned short* __restrict__ B,
    unsigned short* __restrict__ dtr, float* __restrict__ bterm,
    float* __restrict__ cterm, int M, int N, int K) {
  __shared__ short As[128 * 32];
  __shared__ short Bs[128 * 32];
  const int m0 = blockIdx.x * 128;
  const int lane = threadIdx.x & 63;
  const int wv = threadIdx.x >> 6;
  const int wm = (wv >> 1) * 64;
  const int wn = (wv & 1) * 64;
  f32x4 acc[4][4] = {};
  const int row_a = wv * 32 + (lane >> 2);
  const int koff = (lane & 3) * 8;
  const unsigned short* gA = A + (size_t)(m0 + row_a) * K + koff;
  const unsigned short* gB = B + (size_t)row_a * K + koff;
  short* lA = &As[(wv * 32) * 32];
  short* lB = &Bs[(wv * 32) * 32];
  const int r = lane & 15;
  const int q = lane >> 4;
  for (int k0 = 0; k0 < K; k0 += 32) {
    __syncthreads();
    __builtin_amdgcn_global_load_lds((const __attribute__((address_space(1))) void*)(const void*)gA,
                                     (__attribute__((address_space(3))) void*)(void*)lA, 16, 0, 0);
    __builtin_amdgcn_global_load_lds((const __attribute__((address_space(1))) void*)(const void*)(gA + 16 * K),
                                     (__attribute__((address_space(3))) void*)(void*)(lA + 16 * 32), 16, 0, 0);
    __builtin_amdgcn_global_load_lds((const __attribute__((address_space(1))) void*)(const void*)gB,
                                     (__attribute__((address_space(3))) void*)(void*)lB, 16, 0, 0);
    __builtin_amdgcn_global_load_lds((const __attribute__((address_space(1))) void*)(const void*)(gB + 16 * K),
                                     (__attribute__((address_space(3))) void*)(void*)(lB + 16 * 32), 16, 0, 0);
    gA += 32; gB += 32;
    __syncthreads();
    bf16x8 av[4], bv[4];
#pragma unroll
    for (int i = 0; i < 4; ++i)
      av[i] = *(const bf16x8*)&As[(wm + i * 16 + r) * 32 + q * 8];
#pragma unroll
    for (int j = 0; j < 4; ++j)
      bv[j] = *(const bf16x8*)&Bs[(wn + j * 16 + r) * 32 + q * 8];
#pragma unroll
    for (int i = 0; i < 4; ++i)
#pragma unroll
      for (int j = 0; j < 4; ++j)
        acc[i][j] = __builtin_amdgcn_mfma_f32_16x16x32_bf16(av[i], bv[j], acc[i][j], 0, 0, 0);
  }
  // C/D layout: col = lane&15, row = (lane>>4)*4 + reg
#pragma unroll
  for (int i = 0; i < 4; ++i)
#pragma unroll
    for (int j = 0; j < 4; ++j) {
      const int col = wn + j * 16 + r;
#pragma unroll
      for (int t = 0; t < 4; ++t) {
        const int row = m0 + wm + i * 16 + q * 4 + t;
        float v = acc[i][j][t];
        if (col < 64)      dtr[(size_t)row * 64 + col] = f2bf(v);
        else if (col < 72) bterm[(size_t)row * 8 + (col - 64)] = ftanh(v);
        else if (col < 80) cterm[(size_t)row * 8 + (col - 72)] = ftanh(v);
      }
    }
}

// dt GEMM: M=16384, N=512, K=64. Fused: delta = clip(softplus(v + b_dt[n]),1e-4,1)
__global__ __launch_bounds__(256) void gemm_dt128(
    const unsigned short* __restrict__ A,
    const unsigned short* __restrict__ B,
    const float* __restrict__ bdt,
    float* __restrict__ C, int M, int N, int K) {
  __shared__ short As[128 * 32];
  __shared__ short Bs[128 * 32];
  const int m0 = blockIdx.x * 128;
  const int n0 = blockIdx.y * 128;
  const int lane = threadIdx.x & 63;
  const int wv = threadIdx.x >> 6;
  const int wm = (wv >> 1) * 64;
  const int wn = (wv & 1) * 64;
  f32x4 acc[4][4] = {};
  const int row_a = wv * 32 + (lane >> 2);
  const int koff = (lane & 3) * 8;
  const unsigned short* gA = A + (size_t)(m0 + row_a) * K + koff;
  const unsigned short* gB = B + (size_t)(n0 + row_a) * K + koff;
  short* lA = &As[(wv * 32) * 32];
  short* lB = &Bs[(wv * 32) * 32];
  const int r = lane & 15;
  const int q = lane >> 4;
  for (int k0 = 0; k0 < K; k0 += 32) {
    __syncthreads();
    __builtin_amdgcn_global_load_lds((const __attribute__((address_space(1))) void*)(const void*)gA,
                                     (__attribute__((address_space(3))) void*)(void*)lA, 16, 0, 0);
    __builtin_amdgcn_global_load_lds((const __attribute__((address_space(1))) void*)(const void*)(gA + 16 * K),
                                     (__attribute__((address_space(3))) void*)(void*)(lA + 16 * 32), 16, 0, 0);
    __builtin_amdgcn_global_load_lds((const __attribute__((address_space(1))) void*)(const void*)gB,
                                     (__attribute__((address_space(3))) void*)(void*)lB, 16, 0, 0);
    __builtin_amdgcn_global_load_lds((const __attribute__((address_space(1))) void*)(const void*)(gB + 16 * K),
                                     (__attribute__((address_space(3))) void*)(void*)(lB + 16 * 32), 16, 0, 0);
    gA += 32; gB += 32;
    __syncthreads();
    bf16x8 av[4], bv[4];
#pragma unroll
    for (int i = 0; i < 4; ++i)
      av[i] = *(const bf16x8*)&As[(wm + i * 16 + r) * 32 + q * 8];
#pragma unroll
    for (int j = 0; j < 4; ++j)
      bv[j] = *(const bf16x8*)&Bs[(wn + j * 16 + r) * 32 + q * 8];
#pragma unroll
    for (int i = 0; i < 4; ++i)
#pragma unroll
      for (int j = 0; j < 4; ++j)
        acc[i][j] = __builtin_amdgcn_mfma_f32_16x16x32_bf16(av[i], bv[j], acc[i][j], 0, 0, 0);
  }
#pragma unroll
  for (int j = 0; j < 4; ++j) {
    const int col = n0 + wn + j * 16 + r;
    const float bb = bdt[col];
#pragma unroll
    for (int i = 0; i < 4; ++i)
#pragma unroll
      for (int t = 0; t < 4; ++t) {
        float v = acc[i][j][t] + bb;
        float delta = fminf(fmaxf(fsoftplus(v), 1e-4f), 1.f);
        C[(size_t)(m0 + wm + i * 16 + q * 4 + t) * N + col] = delta;
      }
  }
}

// ================= 256x256 8-phase GEMM (big shapes) ======================
// Round-2 structure (measured 42.9-43.2us, 0 bank conflicts):
// reads-at-phase-start -> stage -> [vmcnt] -> barrier -> lgkmcnt(0) -> MFMA.
// C[m,n] = sum_k A[m,k]*B[n,k].  BM=BN=256, BK=64, 8 waves, 128 KiB LDS.
// Slot layout [row(128)][col(64) bf16] with XOR swizzle col^=((row&7)<<3);
// linear gload_lds dest + pre-swizzled global source (involution).
__device__ __forceinline__ void g256_stage(short* lds, int slot,
    const unsigned short* sp, int ktIdx, int wvLds, int K) {
  const unsigned short* s = sp + ktIdx * 64;
  __builtin_amdgcn_global_load_lds((const __attribute__((address_space(1))) void*)s,
      (__attribute__((address_space(3))) void*)(lds + slot * 8192 + wvLds), 16, 0, 0);
  __builtin_amdgcn_global_load_lds((const __attribute__((address_space(1))) void*)(s + (size_t)64 * K),
      (__attribute__((address_space(3))) void*)(lds + slot * 8192 + 4096 + wvLds), 16, 0, 0);
}

template <int PAR, int MH, int NHLO, bool RA, bool RB, int SSLOT, bool VM, bool HINT>
__device__ __forceinline__ void g256_phase(
    short* lds, int aSlotOff, int bSlotOff, int aoff, int boff, int wvLds,
    bf16x8 (&av)[4][2], bf16x8 (&bv)[4][2], f32x4 (&acc)[8][4],
    const unsigned short* sp, int ktIdx, int K) {
  if (RA) {
#pragma unroll
    for (int ii = 0; ii < 4; ++ii) {
      av[ii][0] = *(const bf16x8*)&lds[PAR * 4 * 8192 + aSlotOff + MH * 4096 + ii * 1024 + aoff];
      av[ii][1] = *(const bf16x8*)&lds[PAR * 4 * 8192 + aSlotOff + MH * 4096 + ii * 1024 + (aoff ^ 32)];
    }
  }
  if (RB) {
#pragma unroll
    for (int jj = 0; jj < 2; ++jj) {
      bv[NHLO + jj][0] = *(const bf16x8*)&lds[(PAR * 4 + 2) * 8192 + bSlotOff + (NHLO + jj) * 1024 + boff];
      bv[NHLO + jj][1] = *(const bf16x8*)&lds[(PAR * 4 + 2) * 8192 + bSlotOff + (NHLO + jj) * 1024 + (boff ^ 32)];
    }
  }
  g256_stage(lds, SSLOT, sp, ktIdx, wvLds, K);
  if (HINT) asm volatile("s_waitcnt lgkmcnt(8)");
  if (VM) asm volatile("s_waitcnt vmcnt(4)" ::: "memory");
  __builtin_amdgcn_s_barrier();
  asm volatile("s_waitcnt lgkmcnt(0)" ::: "memory");
  __builtin_amdgcn_s_setprio(1);
#pragma unroll
  for (int ii = 0; ii < 4; ++ii)
#pragma unroll
    for (int jj = 0; jj < 2; ++jj) {
      acc[MH * 4 + ii][NHLO + jj] = __builtin_amdgcn_mfma_f32_16x16x32_bf16(
          av[ii][0], bv[NHLO + jj][0], acc[MH * 4 + ii][NHLO + jj], 0, 0, 0);
      acc[MH * 4 + ii][NHLO + jj] = __builtin_amdgcn_mfma_f32_16x16x32_bf16(
          av[ii][1], bv[NHLO + jj][1], acc[MH * 4 + ii][NHLO + jj], 0, 0, 0);
    }
  __builtin_amdgcn_s_setprio(0);
  __builtin_amdgcn_s_barrier();
}

__global__ __launch_bounds__(512, 2) void gemm256_bt(
    const unsigned short* __restrict__ A,
    const unsigned short* __restrict__ B,
    float* __restrict__ C, int M, int N, int K) {
  __shared__ short lds[8 * 8192];  // 128 KiB
  const int nmt = M >> 8;
  const int bid = blockIdx.x;
  // XCD swizzle for A-panel reuse: each XCD owns (nmt/8) m-tiles x ALL
  // n-tiles, so the 4 blocks sharing an A panel are co-resident on ONE XCD.
  const int g = nmt >> 3;
  const int xcd = bid & 7;
  const int loc = bid >> 3;
  const int mtile = xcd * g + (loc % g);
  const int ntile = loc / g;
  const int m0 = mtile << 8, n0 = ntile << 8;
  const int tid = threadIdx.x;
  const int w = tid >> 6, lane = tid & 63;
  const int r = lane & 15, q = lane >> 4;
  const int wrow = w >> 2, wcol = w & 3;
  // staging: dest row tid>>3, stored col (tid&7)*8 (linear); source col is
  // the swizzle-inverse (XOR involution), stays in the same 128-B line:
  const int srow = tid >> 3;
  const int scol = ((tid & 7) ^ (srow & 7)) << 3;
  const unsigned short* pA0 = A + (size_t)(m0 + srow) * K + scol;
  const unsigned short* pA1 = A + (size_t)(m0 + 128 + srow) * K + scol;
  const unsigned short* pB0 = B + (size_t)(n0 + srow) * K + scol;
  const unsigned short* pB1 = B + (size_t)(n0 + 128 + srow) * K + scol;
  const int wvLds = w * 512;
  const int aSlotOff = wrow * 8192;
  const int bSlotOff = (wcol >> 1) * 8192;
  const int swzc = (q * 8) ^ ((r & 7) << 3);
  const int aoff = r * 64 + swzc;
  const int boff = (wcol & 1) * 4096 + r * 64 + swzc;
  bf16x8 av[4][2], bv[4][2];
  f32x4 acc[8][4] = {};
  const int NT = K >> 6;   // K-tiles (even, >=4)
  const int NI = NT >> 1;
  // prologue: K-tile 0 full (s0-s3) + K-tile 1 B halves (s6,s7)
  g256_stage(lds, 0, pA0, 0, wvLds, K);
  g256_stage(lds, 1, pA1, 0, wvLds, K);
  g256_stage(lds, 2, pB0, 0, wvLds, K);
  g256_stage(lds, 3, pB1, 0, wvLds, K);
  g256_stage(lds, 6, pB0, 1, wvLds, K);
  g256_stage(lds, 7, pB1, 1, wvLds, K);
  asm volatile("s_waitcnt vmcnt(4)" ::: "memory");  // s0-s3 landed
  __builtin_amdgcn_s_barrier();
#pragma unroll 1
  for (int it = 0; it < NI; ++it) {
    const int ktO  = 2 * it + 1;
    const int ktE2 = (2 * it + 2 < NT) ? 2 * it + 2 : NT - 1;  // clamp (tail: dead)
    const int ktO2 = (2 * it + 3 < NT) ? 2 * it + 3 : NT - 1;
    g256_phase<0, 0, 0, true,  true,  4, false, true >(lds, aSlotOff, bSlotOff, aoff, boff, wvLds, av, bv, acc, pA0, ktO,  K);
    g256_phase<0, 0, 2, false, true,  5, false, false>(lds, aSlotOff, bSlotOff, aoff, boff, wvLds, av, bv, acc, pA1, ktO,  K);
    g256_phase<0, 1, 2, true,  false, 2, false, false>(lds, aSlotOff, bSlotOff, aoff, boff, wvLds, av, bv, acc, pB0, ktE2, K);
    g256_phase<0, 1, 0, false, false, 0, true,  false>(lds, aSlotOff, bSlotOff, aoff, boff, wvLds, av, bv, acc, pA0, ktE2, K);
    g256_phase<1, 0, 0, true,  true,  1, false, true >(lds, aSlotOff, bSlotOff, aoff, boff, wvLds, av, bv, acc, pA1, ktE2, K);
    g256_phase<1, 0, 2, false, true,  3, false, false>(lds, aSlotOff, bSlotOff, aoff, boff, wvLds, av, bv, acc, pB1, ktE2, K);
    g256_phase<1, 1, 2, true,  false, 6, false, false>(lds, aSlotOff, bSlotOff, aoff, boff, wvLds, av, bv, acc, pB0, ktO2, K);
    g256_phase<1, 1, 0, false, false, 7, true,  false>(lds, aSlotOff, bSlotOff, aoff, boff, wvLds, av, bv, acc, pB1, ktO2, K);
  }
  asm volatile("s_waitcnt vmcnt(0) lgkmcnt(0)" ::: "memory");
  // epilogue: C/D layout col = lane&15, row = (lane>>4)*4 + reg
  float* Cw = C + (size_t)(m0 + wrow * 128) * N + n0 + wcol * 64;
#pragma unroll
  for (int ii = 0; ii < 8; ++ii)
#pragma unroll
    for (int jj = 0; jj < 4; ++jj)
#pragma unroll
      for (int t = 0; t < 4; ++t)
        Cw[(size_t)(ii * 16 + q * 4 + t) * N + jj * 16 + r] = acc[ii][jj][t];
}

// -------- depthwise conv (k=3, pad=1) + SiLU, rolling-window over 16 rows --
__global__ __launch_bounds__(256) void conv_silu_roll(
    const float* __restrict__ h, const float* __restrict__ Kx, const float* __restrict__ Kz,
    float* __restrict__ xb, unsigned short* __restrict__ xbbf,
    unsigned short* __restrict__ cat) {
  const int c4 = threadIdx.x << 2;          // channel group base (0..1020)
  const int bt = blockIdx.x >> 8;           // batch
  const int lt = blockIdx.x & 255;          // l-tile (16 rows each)
  const int l0 = lt << 4;
  const float* Kp; int c;
  if (c4 < 512) { Kp = Kx; c = c4; } else { Kp = Kz; c = c4 - 512; }
  const float4* K4 = (const float4*)(Kp + c * 3);  // 12 floats, 16B-aligned
  const float4 ka = K4[0], kb = K4[1], kc = K4[2];
  size_t rowbase = ((size_t)bt * 4096 + l0) * 1024 + c4;   // h/cat index, row l0
  size_t xrow    = ((size_t)bt * 4096 + l0) * 512 + c4;    // xb/xbbf index
  const float4 zero = make_float4(0.f, 0.f, 0.f, 0.f);
  float4 um = (l0 > 0) ? *(const float4*)(h + rowbase - 1024) : zero;
  float4 u0 = *(const float4*)(h + rowbase);
#pragma unroll 4
  for (int s = 0; s < 16; ++s) {
    const int l = l0 + s;
    float4 up = (l < 4095) ? *(const float4*)(h + rowbase + 1024) : zero;
    float v0 = um.x * ka.x + u0.x * ka.y + up.x * ka.z;
    float v1 = um.y * ka.w + u0.y * kb.x + up.y * kb.y;
    float v2 = um.z * kb.z + u0.z * kb.w + up.z * kc.x;
    float v3 = um.w * kc.y + u0.w * kc.z + up.w * kc.w;
    float o0 = v0 / (1.f + __expf(-v0));
    float o1 = v1 / (1.f + __expf(-v1));
    float o2 = v2 / (1.f + __expf(-v2));
    float o3 = v3 / (1.f + __expf(-v3));
    ushort4 ob;
    ob.x = f2bf(o0); ob.y = f2bf(o1); ob.z = f2bf(o2); ob.w = f2bf(o3);
    if (c4 < 512) {
      *(float4*)(xb + xrow) = make_float4(o0, o1, o2, o3);
      *(ushort4*)(xbbf + xrow) = ob;
    } else {
      *(ushort4*)(cat + rowbase) = ob;
    }
    um = u0; u0 = up;
    rowbase += 1024; xrow += 512;
  }
}

// ---------------- chunked selective scan (128 chunks x 32 steps) ----------
// delta precomputed (fused into gemm_dt128). ILP upgrades vs round 6:
// (a) bt/ct tiles preloaded into LDS once per block (they are block-uniform;
//     replaces 128 redundant uniform VMEM loads/thread with broadcast
//     ds_reads); (b) delta/xv strided loads batched 8-deep (16 loads in
//     flight instead of 2). Compute order unchanged -> bit-identical.
__global__ __launch_bounds__(256) void scan_p1(
    const float* __restrict__ delta_in, const float* __restrict__ bterm,
    const float* __restrict__ xb, const float* __restrict__ A_log,
    float* __restrict__ Aprod, float* __restrict__ Bpart) {
  __shared__ float btl[256];   // [step 0..31][s 0..7]
  int tid = threadIdx.x;
  int gid = blockIdx.x;
  int chunk = gid & 127, half = (gid >> 7) & 1, b = gid >> 8;
  int c = half * 256 + tid;
  int l0 = chunk * 32;
  btl[tid] = bterm[((size_t)b * 4096 + l0) * 8 + tid];
  float4 a0 = *(const float4*)&A_log[c * 8];
  float4 a1 = *(const float4*)&A_log[c * 8 + 4];
  float na[8] = {a0.x, a0.y, a0.z, a0.w, a1.x, a1.y, a1.z, a1.w};
#pragma unroll
  for (int s = 0; s < 8; ++s) na[s] = -(fsoftplus(na[s]) + 1e-4f);
  __syncthreads();
  size_t base = ((size_t)b * 4096 + l0) * 512 + c;
  float S[8] = {}, Ap[8] = {1.f, 1.f, 1.f, 1.f, 1.f, 1.f, 1.f, 1.f};
  for (int ib = 0; ib < 32; ib += 8) {
    float dl8[8], xv8[8];
#pragma unroll
    for (int j = 0; j < 8; ++j) {
      dl8[j] = delta_in[base + (size_t)j * 512];
      xv8[j] = xb[base + (size_t)j * 512];
    }
#pragma unroll
    for (int j = 0; j < 8; ++j) {
      float delta = dl8[j], xv = xv8[j];
      const float* bt = &btl[(ib + j) * 8];
#pragma unroll
      for (int s = 0; s < 8; ++s) {
        float dec = fminf(fmaxf(__expf(delta * na[s]), 1e-4f), 1.f);
        float btx = bt[s] * xv;
        S[s] = dec * S[s] + (btx - dec * btx);
        Ap[s] *= dec;
      }
    }
    base += (size_t)8 * 512;
  }
  size_t o = (size_t)chunk * 16384 + ((size_t)(b * 512 + c)) * 8;
  *(float4*)&Aprod[o]     = make_float4(Ap[0], Ap[1], Ap[2], Ap[3]);
  *(float4*)&Aprod[o + 4] = make_float4(Ap[4], Ap[5], Ap[6], Ap[7]);
  *(float4*)&Bpart[o]     = make_float4(S[0], S[1], S[2], S[3]);
  *(float4*)&Bpart[o + 4] = make_float4(S[4], S[5], S[6], S[7]);
}

// 256 blocks x 64 threads: same 16384 series, spread over all 256 CUs.
__global__ __launch_bounds__(64) void scan_p2(
    const float* __restrict__ Aprod, const float* __restrict__ Bpart,
    float* __restrict__ initst) {
  int t = blockIdx.x * 64 + threadIdx.x;  // 16384 threads: one (b,c,s)
  float st = 0.f;
  for (int cb = 0; cb < 128; cb += 8) {
    float a[8], bb[8];
#pragma unroll
    for (int j = 0; j < 8; ++j) {
      size_t o = (size_t)(cb + j) * 16384 + t;
      a[j] = Aprod[o]; bb[j] = Bpart[o];
    }
#pragma unroll
    for (int j = 0; j < 8; ++j) {
      size_t o = (size_t)(cb + j) * 16384 + t;
      initst[o] = st;
      st = a[j] * st + bb[j];
    }
  }
}

__global__ __launch_bounds__(256) void scan_p3(
    const float* __restrict__ delta_in, const float* __restrict__ bterm,
    const float* __restrict__ cterm, const float* __restrict__ xb,
    const float* __restrict__ A_log, const float* __restrict__ Dp,
    const float* __restrict__ initst, unsigned short* __restrict__ cat) {
  __shared__ float btl[256], ctl[256];   // [step 0..31][s 0..7]
  int tid = threadIdx.x;
  int gid = blockIdx.x;
  int chunk = gid & 127, half = (gid >> 7) & 1, b = gid >> 8;
  int c = half * 256 + tid;
  int l0 = chunk * 32;
  {
    size_t bb = ((size_t)b * 4096 + l0) * 8 + tid;
    btl[tid] = bterm[bb];
    ctl[tid] = cterm[bb];
  }
  float4 a0 = *(const float4*)&A_log[c * 8];
  float4 a1 = *(const float4*)&A_log[c * 8 + 4];
  float na[8] = {a0.x, a0.y, a0.z, a0.w, a1.x, a1.y, a1.z, a1.w};
#pragma unroll
  for (int s = 0; s < 8; ++s) na[s] = -(fsoftplus(na[s]) + 1e-4f);
  float Dv = Dp[c];
  size_t o = (size_t)chunk * 16384 + ((size_t)(b * 512 + c)) * 8;
  float4 s0 = *(const float4*)&initst[o];
  float4 s1 = *(const float4*)&initst[o + 4];
  float S[8] = {s0.x, s0.y, s0.z, s0.w, s1.x, s1.y, s1.z, s1.w};
  __syncthreads();
  size_t base  = ((size_t)b * 4096 + l0) * 512 + c;
  size_t cbase = ((size_t)b * 4096 + l0) * 1024 + c;   // y -> cat[..., :512]
  for (int ib = 0; ib < 32; ib += 8) {
    float dl8[8], xv8[8];
#pragma unroll
    for (int j = 0; j < 8; ++j) {
      dl8[j] = delta_in[base + (size_t)j * 512];
      xv8[j] = xb[base + (size_t)j * 512];
    }
#pragma unroll
    for (int j = 0; j < 8; ++j) {
      float delta = dl8[j], xv = xv8[j];
      const float* bt = &btl[(ib + j) * 8];
      const float* ct = &ctl[(ib + j) * 8];
      float acc = Dv * xv;
#pragma unroll
      for (int s = 0; s < 8; ++s) {
        float dec = fminf(fmaxf(__expf(delta * na[s]), 1e-4f), 1.f);
        float btx = bt[s] * xv;
        S[s] = dec * S[s] + (btx - dec * btx);
        acc += S[s] * ct[s];
      }
      cat[cbase + (size_t)(ib + j) * 1024] = f2bf(acc);
    }
    base += (size_t)8 * 512;
  }
}

// ---------------- launch ----------------
extern "C" void kernel_launch(void* const* d_in, const int* in_sizes, int n_in,
                              void* d_out, int out_size, void* d_ws, size_t ws_size,
                              hipStream_t stream) {
  (void)in_sizes; (void)n_in; (void)out_size; (void)ws_size;
  const float* x       = (const float*)d_in[0];
  const float* W_in    = (const float*)d_in[1];
  const float* Kx      = (const float*)d_in[2];
  const float* Kz      = (const float*)d_in[3];
  const float* W_xproj = (const float*)d_in[4];
  const float* W_dt    = (const float*)d_in[5];
  const float* b_dt    = (const float*)d_in[6];
  const float* A_log   = (const float*)d_in[7];
  const float* Dp      = (const float*)d_in[8];
  const float* W_out   = (const float*)d_in[9];
  float* out = (float*)d_out;

  // workspace layout (133.4 MB) with dead-buffer overlays
  char* w = (char*)d_ws;
  unsigned short* xbf  = (unsigned short*)(w);               // 33.5MB x bf16; reused as cat
  float* xb    = (float*)(w + 33554432);                     // 33.5MB fp32 xb (scan)
  float* draw  = (float*)(w + 67108864);                     // 33.5MB delta (fused softplus)
  float* bterm = (float*)(w + 100663296);                    // 0.5MB
  float* cterm = (float*)(w + 101187584);                    // 0.5MB
  float* Aprod = (float*)(w + 101711872);                    // 8MB [chunk][bcs]
  float* Bpart = (float*)(w + 110100480);                    // 8MB
  float* initst = (float*)(w + 118489088);                   // 8MB
  unsigned short* winbf  = (unsigned short*)(w + 126877696); // 2MB
  unsigned short* woutbf = (unsigned short*)(w + 128974848); // 2MB
  unsigned short* dtr    = (unsigned short*)(w + 131072000); // 2MB (16384x64 bf16)
  unsigned short* wxp_bf = (unsigned short*)(w + 133169152); // 128KB
  unsigned short* wd_bf  = (unsigned short*)(w + 133300224); // 64KB  (end 133365760)
  unsigned short* xbbf = (unsigned short*)Aprod;             // 16.8MB overlay; dead before scan
  float* h = out;  // d_out doubles as h scratch (fully rewritten by final GEMM)

  // all fp32->bf16 conversions in one launch
  prep_all<<<18720, 256, 0, stream>>>(x, W_in, W_out, W_dt, W_xproj,
                                      xbf, winbf, woutbf, wd_bf, wxp_bf);

  // big GEMMs: 256x256 8-phase kernel, grid = (16384/256)*(1024/256) = 256
  gemm256_bt<<<256, 512, 0, stream>>>(xbf, winbf, h, 16384, 1024, 1024);

  conv_silu_roll<<<1024, 256, 0, stream>>>(h, Kx, Kz, xb, xbbf, xbf /*cat*/);

  // proj GEMM with fused dtr/bterm/cterm epilogue (proj never materialized)
  gemm_proj128<<<128, 256, 0, stream>>>(xbbf, wxp_bf, dtr, bterm, cterm, 16384, 128, 512);
  // dt GEMM with fused softplus+clip epilogue -> delta (into draw buffer)
  gemm_dt128<<<dim3(128, 4), 256, 0, stream>>>(dtr, wd_bf, b_dt, draw, 16384, 512, 64);

  scan_p1<<<1024, 256, 0, stream>>>(draw, bterm, xb, A_log, Aprod, Bpart);
  scan_p2<<<256, 64, 0, stream>>>(Aprod, Bpart, initst);
  scan_p3<<<1024, 256, 0, stream>>>(draw, bterm, cterm, xb, A_log, Dp, initst, xbf /*cat*/);

  gemm256_bt<<<256, 512, 0, stream>>>(xbf, woutbf, out, 16384, 1024, 1024);
}